// Round 1
// baseline (477.846 us; speedup 1.0000x reference)
//
#include <hip/hip_runtime.h>

typedef unsigned short u16;
typedef unsigned int u32;
typedef __attribute__((ext_vector_type(4))) float f32x4;
typedef __attribute__((ext_vector_type(8))) __bf16 bf16x8;
typedef __attribute__((ext_vector_type(4))) u16 u16x4;

// round-to-nearest-even f32 -> bf16 (no NaN handling needed; inputs finite)
__device__ __forceinline__ u16 f2bf(float f) {
  u32 u = __float_as_uint(f);
  u32 r = (u + 0x7fffu + ((u >> 16) & 1u)) >> 16;
  return (u16)r;
}

// threshold arrives as a 1-element int array per harness convention; hedge in
// case it is actually stored as float bits.
__device__ __forceinline__ float load_thr(const int* p) {
  int iv = *p;
  float fv = __int_as_float(iv);
  if (fv >= 1.0f && fv <= 1.0e6f) return fv;
  return (float)iv;
}

__device__ __forceinline__ void gload_lds16(const void* g, void* l) {
  __builtin_amdgcn_global_load_lds(
      (const __attribute__((address_space(1))) void*)g,
      (__attribute__((address_space(3))) void*)l, 16, 0, 0);
}

// ---------------- colmax over rows of x ----------------
__global__ void k_init_cm(u32* cm, int K) {
  int i = blockIdx.x * 256 + threadIdx.x;
  if (i < K) cm[i] = 0u;
}

__global__ __launch_bounds__(256) void k_colmax(const float* __restrict__ x,
                                                u32* __restrict__ cm, int M,
                                                int K, int rpb) {
  int c4 = blockIdx.x * 256 + threadIdx.x;  // float4 index within a row
  int r0 = blockIdx.y * rpb;
  int r1 = r0 + rpb;
  if (r1 > M) r1 = M;
  f32x4 mx = {0.f, 0.f, 0.f, 0.f};
  for (int r = r0; r < r1; ++r) {
    f32x4 v = *(const f32x4*)&x[(size_t)r * K + (size_t)c4 * 4];
#pragma unroll
    for (int i = 0; i < 4; ++i) mx[i] = fmaxf(mx[i], fabsf(v[i]));
  }
#pragma unroll
  for (int i = 0; i < 4; ++i)
    atomicMax(&cm[c4 * 4 + i], __float_as_uint(mx[i]));
}

// ---------------- row-wise quant-dequant -> bf16 operand ----------------
// one block per row; K must be 4096 (16 elems/thread).
// exclude_outlier_from_max=1 for x (x_int zeroed on outlier cols before max),
// 0 for W (scale from full row). Outlier columns pass through at full
// precision (folds the fp outlier GEMM into the main GEMM).
__global__ __launch_bounds__(256) void k_quant(
    const float* __restrict__ src, const u32* __restrict__ cm,
    const int* __restrict__ thr_i, u16* __restrict__ dst, int K,
    int exclude_outlier_from_max) {
  int row = blockIdx.x;
  int tid = threadIdx.x;
  float thr = load_thr(thr_i);
  const float* sr = src + (size_t)row * K;
  const float* cmf = (const float*)cm;  // |x| bits compare as floats

  float v[16];
  u32 omask = 0;
  float lmax = 0.f;
#pragma unroll
  for (int j = 0; j < 4; ++j) {
    int c4 = j * 256 + tid;
    f32x4 val = *(const f32x4*)&sr[c4 * 4];
    f32x4 cv = *(const f32x4*)&cmf[c4 * 4];
#pragma unroll
    for (int i = 0; i < 4; ++i) {
      float xv = val[i];
      v[j * 4 + i] = xv;
      bool is_out = cv[i] > thr;
      if (is_out) omask |= 1u << (j * 4 + i);
      if (!is_out || !exclude_outlier_from_max)
        lmax = fmaxf(lmax, fabsf(xv));
    }
  }
  // block max reduction
  float m = lmax;
#pragma unroll
  for (int off = 32; off >= 1; off >>= 1) m = fmaxf(m, __shfl_down(m, off));
  __shared__ float red[4];
  int lane = tid & 63, wv = tid >> 6;
  if (lane == 0) red[wv] = m;
  __syncthreads();
  float rm = fmaxf(fmaxf(red[0], red[1]), fmaxf(red[2], red[3]));
  float s = fmaxf(rm / 127.0f, 1e-8f);

#pragma unroll
  for (int j = 0; j < 4; ++j) {
    int c4 = j * 256 + tid;
    u16x4 ov;
#pragma unroll
    for (int i = 0; i < 4; ++i) {
      float xv = v[j * 4 + i];
      float dq;
      if (omask & (1u << (j * 4 + i))) {
        dq = xv;  // outlier column: full-precision path
      } else {
        float q = rintf(xv / s);  // round-half-even, matches jnp.round
        q = fminf(fmaxf(q, -127.f), 127.f);
        dq = q * s;
      }
      ov[i] = f2bf(dq);
    }
    *(u16x4*)&dst[(size_t)row * K + c4 * 4] = ov;
  }
}

// ---------------- bf16 GEMM (NT): out = A @ B^T + bias ----------------
// m97 structure: 128x128 tile, BK=64, 4 waves (2x2), 4x4 16x16x32 MFMA frags,
// global_load_lds width 16, single-buffered LDS, 2 barriers per K-step.
#define BM 128
#define BN 128
#define BKK 64

__global__ __launch_bounds__(256) void k_gemm(const u16* __restrict__ Aq,
                                              const u16* __restrict__ Bq,
                                              const float* __restrict__ bias,
                                              float* __restrict__ out, int M,
                                              int N, int K) {
  __shared__ u16 As[BM * BKK];
  __shared__ u16 Bs[BN * BKK];
  int tid = threadIdx.x;
  int bm = blockIdx.x, bn = blockIdx.y;
  int lane = tid & 63, wave = tid >> 6;
  int wr = (wave >> 1) * 64, wc = (wave & 1) * 64;
  int r0 = bm * BM, c0 = bn * BN;

  f32x4 acc[4][4] = {};

  for (int kb = 0; kb < K; kb += BKK) {
#pragma unroll
    for (int it = 0; it < 4; ++it) {
      int e = it * 256 + tid;
      int row = e >> 3, c8 = (e & 7) << 3;
      gload_lds16(&Aq[(size_t)(r0 + row) * K + kb + c8], &As[row * BKK + c8]);
    }
#pragma unroll
    for (int it = 0; it < 4; ++it) {
      int e = it * 256 + tid;
      int row = e >> 3, c8 = (e & 7) << 3;
      gload_lds16(&Bq[(size_t)(c0 + row) * K + kb + c8], &Bs[row * BKK + c8]);
    }
    __syncthreads();
#pragma unroll
    for (int ks = 0; ks < 2; ++ks) {
      int kc = ks * 32 + (lane >> 4) * 8;
      bf16x8 af[4], bfv[4];
#pragma unroll
      for (int i = 0; i < 4; ++i)
        af[i] = *(const bf16x8*)&As[(wr + i * 16 + (lane & 15)) * BKK + kc];
#pragma unroll
      for (int j = 0; j < 4; ++j)
        bfv[j] = *(const bf16x8*)&Bs[(wc + j * 16 + (lane & 15)) * BKK + kc];
#pragma unroll
      for (int i = 0; i < 4; ++i)
#pragma unroll
        for (int j = 0; j < 4; ++j)
          acc[i][j] = __builtin_amdgcn_mfma_f32_16x16x32_bf16(
              af[i], bfv[j], acc[i][j], 0, 0, 0);
    }
    __syncthreads();
  }

  // C/D layout (m89/m91 verified): col = lane&15, row = (lane>>4)*4 + reg
  int lr = (lane >> 4) * 4, lc = lane & 15;
#pragma unroll
  for (int i = 0; i < 4; ++i) {
#pragma unroll
    for (int r = 0; r < 4; ++r) {
      int gm = r0 + wr + i * 16 + lr + r;
      float* orow = out + (size_t)gm * N;
#pragma unroll
      for (int j = 0; j < 4; ++j) {
        int gn = c0 + wc + j * 16 + lc;
        orow[gn] = acc[i][j][r] + bias[gn];
      }
    }
  }
}

extern "C" void kernel_launch(void* const* d_in, const int* in_sizes, int n_in,
                              void* d_out, int out_size, void* d_ws,
                              size_t ws_size, hipStream_t stream) {
  const float* x = (const float*)d_in[0];
  const float* W = (const float*)d_in[1];
  const float* bias = (const float*)d_in[2];
  const int* thr = (const int*)d_in[3];
  float* out = (float*)d_out;

  int N = in_sizes[2];          // bias length
  int K = in_sizes[1] / N;      // W is [N,K]
  int M = in_sizes[0] / K;      // x is [M,K]

  // workspace layout: colmax (K u32) | A bf16 [M,K] | B bf16 [N,K]
  u32* cm = (u32*)d_ws;
  u16* Aq = (u16*)((char*)d_ws + 16384);
  u16* Bq = (u16*)((char*)d_ws + 16384 + (size_t)M * K * sizeof(u16));

  k_init_cm<<<dim3((K + 255) / 256), dim3(256), 0, stream>>>(cm, K);

  {
    int gx = K / 1024;  // each block covers 1024 columns (256 threads x f32x4)
    int gy = 128;
    int rpb = (M + gy - 1) / gy;
    k_colmax<<<dim3(gx, gy), dim3(256), 0, stream>>>(x, cm, M, K, rpb);
  }

  k_quant<<<dim3(M), dim3(256), 0, stream>>>(x, cm, thr, Aq, K, 1);
  k_quant<<<dim3(N), dim3(256), 0, stream>>>(W, cm, thr, Bq, K, 0);

  k_gemm<<<dim3(M / BM, N / BN), dim3(256), 0, stream>>>(Aq, Bq, bias, out, M,
                                                         N, K);
}

// Round 2
// 343.602 us; speedup vs baseline: 1.3907x; 1.3907x over previous
//
#include <hip/hip_runtime.h>

typedef unsigned short u16;
typedef unsigned int u32;
typedef __attribute__((ext_vector_type(4))) float f32x4;
typedef __attribute__((ext_vector_type(8))) __bf16 bf16x8;
typedef __attribute__((ext_vector_type(4))) u16 u16x4;

__device__ __forceinline__ u16 f2bf(float f) {
  u32 u = __float_as_uint(f);
  u32 r = (u + 0x7fffu + ((u >> 16) & 1u)) >> 16;
  return (u16)r;
}

__device__ __forceinline__ float load_thr(const int* p) {
  int iv = *p;
  float fv = __int_as_float(iv);
  if (fv >= 1.0f && fv <= 1.0e6f) return fv;
  return (float)iv;
}

__device__ __forceinline__ void gload_lds16(const void* g, void* l) {
  __builtin_amdgcn_global_load_lds(
      (const __attribute__((address_space(1))) void*)g,
      (__attribute__((address_space(3))) void*)l, 16, 0, 0);
}

// ---------------- colmax over rows of x ----------------
__global__ void k_init_cm(u32* cm, int K) {
  int i = blockIdx.x * 256 + threadIdx.x;
  if (i < K) cm[i] = 0u;
}

__global__ __launch_bounds__(256) void k_colmax(const float* __restrict__ x,
                                                u32* __restrict__ cm, int M,
                                                int K, int rpb) {
  int c4 = blockIdx.x * 256 + threadIdx.x;
  int r0 = blockIdx.y * rpb;
  int r1 = r0 + rpb;
  if (r1 > M) r1 = M;
  f32x4 mx = {0.f, 0.f, 0.f, 0.f};
  for (int r = r0; r < r1; ++r) {
    f32x4 v = *(const f32x4*)&x[(size_t)r * K + (size_t)c4 * 4];
#pragma unroll
    for (int i = 0; i < 4; ++i) mx[i] = fmaxf(mx[i], fabsf(v[i]));
  }
#pragma unroll
  for (int i = 0; i < 4; ++i)
    atomicMax(&cm[c4 * 4 + i], __float_as_uint(mx[i]));
}

// ---------------- row-wise quant-dequant -> bf16 operand ----------------
__global__ __launch_bounds__(256) void k_quant(
    const float* __restrict__ src, const u32* __restrict__ cm,
    const int* __restrict__ thr_i, u16* __restrict__ dst, int K,
    int exclude_outlier_from_max) {
  int row = blockIdx.x;
  int tid = threadIdx.x;
  float thr = load_thr(thr_i);
  const float* sr = src + (size_t)row * K;
  const float* cmf = (const float*)cm;

  float v[16];
  u32 omask = 0;
  float lmax = 0.f;
#pragma unroll
  for (int j = 0; j < 4; ++j) {
    int c4 = j * 256 + tid;
    f32x4 val = *(const f32x4*)&sr[c4 * 4];
    f32x4 cv = *(const f32x4*)&cmf[c4 * 4];
#pragma unroll
    for (int i = 0; i < 4; ++i) {
      float xv = val[i];
      v[j * 4 + i] = xv;
      bool is_out = cv[i] > thr;
      if (is_out) omask |= 1u << (j * 4 + i);
      if (!is_out || !exclude_outlier_from_max) lmax = fmaxf(lmax, fabsf(xv));
    }
  }
  float m = lmax;
#pragma unroll
  for (int off = 32; off >= 1; off >>= 1) m = fmaxf(m, __shfl_down(m, off));
  __shared__ float red[4];
  int lane = tid & 63, wv = tid >> 6;
  if (lane == 0) red[wv] = m;
  __syncthreads();
  float rm = fmaxf(fmaxf(red[0], red[1]), fmaxf(red[2], red[3]));
  float s = fmaxf(rm / 127.0f, 1e-8f);

#pragma unroll
  for (int j = 0; j < 4; ++j) {
    int c4 = j * 256 + tid;
    u16x4 ov;
#pragma unroll
    for (int i = 0; i < 4; ++i) {
      float xv = v[j * 4 + i];
      float dq;
      if (omask & (1u << (j * 4 + i))) {
        dq = xv;
      } else {
        float q = rintf(xv / s);
        q = fminf(fmaxf(q, -127.f), 127.f);
        dq = q * s;
      }
      ov[i] = f2bf(dq);
    }
    *(u16x4*)&dst[(size_t)row * K + c4 * 4] = ov;
  }
}

// ---------------- 256x256 8-phase bf16 GEMM (NT): out = A @ B^T + bias ----
// m201 template: BM=BN=256, BK=64, 8 waves (2x4), per-wave 128x64 output,
// 128 KiB LDS dbuf, st_16x32 swizzle (source-side pre-swizzle + read XOR),
// counted vmcnt(4) at phases 4/8, setprio around MFMA clusters, XCD swizzle.
#define BM 256
#define BN 256

__global__ __launch_bounds__(512, 2) void k_gemm8(
    const u16* __restrict__ Aq, const u16* __restrict__ Bq,
    const float* __restrict__ bias, float* __restrict__ out, int M, int N,
    int K) {
  extern __shared__ u16 lds_raw[];
  // [buf][op A=0/B=1][half][128*64 u16] ; total 128 KiB
  u16(*lds)[2][2][128 * 64] = (u16(*)[2][2][128 * 64])lds_raw;

  int tid = threadIdx.x;
  int lane = tid & 63, wave = tid >> 6;
  int wm = wave >> 2, wn = wave & 3;  // 2 x 4 wave grid

  // T1: bijective XCD swizzle (nwg % 8 == 0)
  int nwg = gridDim.x;
  int bid = blockIdx.x;
  int swz = (bid & 7) * (nwg >> 3) + (bid >> 3);
  int nbn = N / BN;
  int bm = swz / nbn, bn = swz % nbn;
  int r0 = bm * BM, c0 = bn * BN;

  // staging: per thread 2x global_load_lds(16B) per half-tile (128x64 u16).
  // LDS dest linear (granule g = li*512+tid); global source pre-swizzled so
  // LDS granule g holds linear-granule swz(g), swz(g)=g^(((g>>5)&1)<<1).
  int gin = tid & 63;
  int sg = gin ^ (((gin >> 5) & 1) << 1);
  int s0 = (tid & ~63) | sg;
  int s1 = ((512 + tid) & ~63) | sg;
  int row0s = s0 >> 3, col0e = (s0 & 7) << 3;  // element col (granule=8 u16)
  int row1s = s1 >> 3, col1e = (s1 & 7) << 3;

#define STAGE(dstp, srcb, rowbase, kb)                                        \
  {                                                                           \
    gload_lds16(&(srcb)[(size_t)((rowbase) + row0s) * K + (kb) + col0e],      \
                &(dstp)[(size_t)tid * 8]);                                    \
    gload_lds16(&(srcb)[(size_t)((rowbase) + row1s) * K + (kb) + col1e],      \
                &(dstp)[(size_t)(512 + tid) * 8]);                            \
  }

  // ds_read of one 16x16x32 fragment (8 bf16 = 16B), with T2 read-side XOR
#define LDA(dst, buf, i, ks)                                                  \
  {                                                                           \
    int rl = (i) * 16 + (lane & 15);                                          \
    int off = rl * 128 + (ks) * 64 + ((lane >> 4) << 4);                      \
    off ^= (rl & 4) << 3;                                                     \
    dst = *(const bf16x8*)((const char*)lds[buf][0][wm] + off);               \
  }
#define LDB(dst, buf, j, ks)                                                  \
  {                                                                           \
    int rl = ((wn & 1) << 6) + (j) * 16 + (lane & 15);                        \
    int off = rl * 128 + (ks) * 64 + ((lane >> 4) << 4);                      \
    off ^= (rl & 4) << 3;                                                     \
    dst = *(const bf16x8*)((const char*)lds[buf][1][wn >> 1] + off);          \
  }

#define MF(i, j, av, bv) \
  acc[i][j] = __builtin_amdgcn_mfma_f32_16x16x32_bf16(av, bv, acc[i][j], 0, 0, 0)

  // one phase: quadrant q of buffer buf over full K=64; 16 MFMA
#define PHASE(buf, q, PREF, TAILWAIT)                                         \
  {                                                                           \
    if ((q) == 0) {                                                           \
      LDB(Bf[0], buf, 0, 0); LDB(Bf[1], buf, 1, 0);                           \
      LDB(Bf[2], buf, 2, 0); LDB(Bf[3], buf, 3, 0);                           \
      LDB(Bf[4], buf, 0, 1); LDB(Bf[5], buf, 1, 1);                           \
      LDB(Bf[6], buf, 2, 1); LDB(Bf[7], buf, 3, 1);                           \
    }                                                                         \
    bf16x8 a00, a01, a10, a11;                                                \
    LDA(a00, buf, 2 * (q), 0);                                                \
    LDA(a01, buf, 2 * (q), 1);                                                \
    LDA(a10, buf, 2 * (q) + 1, 0);                                            \
    LDA(a11, buf, 2 * (q) + 1, 1);                                            \
    PREF;                                                                     \
    __builtin_amdgcn_s_barrier();                                             \
    asm volatile("s_waitcnt lgkmcnt(0)" ::: "memory");                        \
    __builtin_amdgcn_sched_barrier(0);                                        \
    __builtin_amdgcn_s_setprio(1);                                            \
    MF(2 * (q), 0, a00, Bf[0]);                                               \
    MF(2 * (q), 1, a00, Bf[1]);                                               \
    MF(2 * (q), 2, a00, Bf[2]);                                               \
    MF(2 * (q), 3, a00, Bf[3]);                                               \
    MF(2 * (q) + 1, 0, a10, Bf[0]);                                           \
    MF(2 * (q) + 1, 1, a10, Bf[1]);                                           \
    MF(2 * (q) + 1, 2, a10, Bf[2]);                                           \
    MF(2 * (q) + 1, 3, a10, Bf[3]);                                           \
    MF(2 * (q), 0, a01, Bf[4]);                                               \
    MF(2 * (q), 1, a01, Bf[5]);                                               \
    MF(2 * (q), 2, a01, Bf[6]);                                               \
    MF(2 * (q), 3, a01, Bf[7]);                                               \
    MF(2 * (q) + 1, 0, a11, Bf[4]);                                           \
    MF(2 * (q) + 1, 1, a11, Bf[5]);                                           \
    MF(2 * (q) + 1, 2, a11, Bf[6]);                                           \
    MF(2 * (q) + 1, 3, a11, Bf[7]);                                           \
    __builtin_amdgcn_s_setprio(0);                                            \
    __builtin_amdgcn_sched_barrier(0);                                        \
    TAILWAIT;                                                                 \
    __builtin_amdgcn_s_barrier();                                             \
  }

  f32x4 acc[8][4] = {};
  bf16x8 Bf[8];

  // prologue: tile0 full into buf0, tile1 B-halves into buf1
  STAGE(lds[0][0][0], Aq, r0, 0);
  STAGE(lds[0][0][1], Aq, r0 + 128, 0);
  STAGE(lds[0][1][0], Bq, c0, 0);
  STAGE(lds[0][1][1], Bq, c0 + 128, 0);
  STAGE(lds[1][1][0], Bq, c0, 64);
  STAGE(lds[1][1][1], Bq, c0 + 128, 64);
  asm volatile("s_waitcnt vmcnt(4)" ::: "memory");
  __builtin_amdgcn_s_barrier();

  int nit = K / 128;  // 2 K-tiles per iteration
  for (int it = 0; it < nit; ++it) {
    int kt1 = it * 128 + 64;  // tile t+1 (always < K)
    int kb2 = it * 128 + 128;
    kb2 = (kb2 < K) ? kb2 : 0;  // tile t+2 (clamped; unused if OOB)
    int kb3 = it * 128 + 192;
    kb3 = (kb3 < K) ? kb3 : 0;  // tile t+3 (clamped)
    // phases 1-4: compute tile t from buf0
    PHASE(0, 0, STAGE(lds[1][0][0], Aq, r0, kt1), );
    PHASE(0, 1, STAGE(lds[1][0][1], Aq, r0 + 128, kt1), );
    PHASE(0, 2, STAGE(lds[0][1][0], Bq, c0, kb2), );
    PHASE(0, 3, STAGE(lds[0][1][1], Bq, c0 + 128, kb2),
          asm volatile("s_waitcnt vmcnt(4)" ::: "memory"));
    // phases 5-8: compute tile t+1 from buf1
    PHASE(1, 0, STAGE(lds[0][0][0], Aq, r0, kb2), );
    PHASE(1, 1, STAGE(lds[0][0][1], Aq, r0 + 128, kb2), );
    PHASE(1, 2, STAGE(lds[1][1][0], Bq, c0, kb3), );
    PHASE(1, 3, STAGE(lds[1][1][1], Bq, c0 + 128, kb3),
          asm volatile("s_waitcnt vmcnt(4)" ::: "memory"));
  }

  // epilogue: C/D layout col=lane&15, row=(lane>>4)*4+reg
  int lr = (lane >> 4) << 2, lc = lane & 15;
  float bv[4];
#pragma unroll
  for (int j = 0; j < 4; ++j) bv[j] = bias[c0 + wn * 64 + j * 16 + lc];
#pragma unroll
  for (int i = 0; i < 8; ++i) {
#pragma unroll
    for (int r = 0; r < 4; ++r) {
      int gm = r0 + wm * 128 + i * 16 + lr + r;
      float* orow = out + (size_t)gm * N + c0 + wn * 64 + lc;
#pragma unroll
      for (int j = 0; j < 4; ++j) orow[j * 16] = acc[i][j][r] + bv[j];
    }
  }
}

extern "C" void kernel_launch(void* const* d_in, const int* in_sizes, int n_in,
                              void* d_out, int out_size, void* d_ws,
                              size_t ws_size, hipStream_t stream) {
  const float* x = (const float*)d_in[0];
  const float* W = (const float*)d_in[1];
  const float* bias = (const float*)d_in[2];
  const int* thr = (const int*)d_in[3];
  float* out = (float*)d_out;

  int N = in_sizes[2];
  int K = in_sizes[1] / N;
  int M = in_sizes[0] / K;

  u32* cm = (u32*)d_ws;
  u16* Aq = (u16*)((char*)d_ws + 16384);
  u16* Bq = (u16*)((char*)d_ws + 16384 + (size_t)M * K * sizeof(u16));

  k_init_cm<<<dim3((K + 255) / 256), dim3(256), 0, stream>>>(cm, K);

  {
    int gx = K / 1024;
    int gy = 128;
    int rpb = (M + gy - 1) / gy;
    k_colmax<<<dim3(gx, gy), dim3(256), 0, stream>>>(x, cm, M, K, rpb);
  }

  k_quant<<<dim3(M), dim3(256), 0, stream>>>(x, cm, thr, Aq, K, 1);
  k_quant<<<dim3(N), dim3(256), 0, stream>>>(W, cm, thr, Bq, K, 0);

  (void)hipFuncSetAttribute((const void*)k_gemm8,
                            hipFuncAttributeMaxDynamicSharedMemorySize,
                            131072);
  int nwg = (M / BM) * (N / BN);
  k_gemm8<<<dim3(nwg), dim3(512), 131072, stream>>>(Aq, Bq, bias, out, M, N,
                                                    K);
}

// Round 3
// 322.265 us; speedup vs baseline: 1.4828x; 1.0662x over previous
//
#include <hip/hip_runtime.h>

typedef unsigned short u16;
typedef unsigned int u32;
typedef __attribute__((ext_vector_type(4))) float f32x4;
typedef __attribute__((ext_vector_type(8))) __bf16 bf16x8;
typedef __attribute__((ext_vector_type(4))) u16 u16x4;

__device__ __forceinline__ u16 f2bf(float f) {
  u32 u = __float_as_uint(f);
  u32 r = (u + 0x7fffu + ((u >> 16) & 1u)) >> 16;
  return (u16)r;
}

__device__ __forceinline__ float load_thr(const int* p) {
  int iv = *p;
  float fv = __int_as_float(iv);
  if (fv >= 1.0f && fv <= 1.0e6f) return fv;
  return (float)iv;
}

__device__ __forceinline__ void gload_lds16(const void* g, void* l) {
  __builtin_amdgcn_global_load_lds(
      (const __attribute__((address_space(1))) void*)g,
      (__attribute__((address_space(3))) void*)l, 16, 0, 0);
}

// ---------------- colmax over rows of x ----------------
__global__ void k_init_cm(u32* cm, int K) {
  int i = blockIdx.x * 256 + threadIdx.x;
  if (i < K) cm[i] = 0u;
}

__global__ __launch_bounds__(256) void k_colmax(const float* __restrict__ x,
                                                u32* __restrict__ cm, int M,
                                                int K, int rpb) {
  int c4 = blockIdx.x * 256 + threadIdx.x;
  int r0 = blockIdx.y * rpb;
  int r1 = r0 + rpb;
  if (r1 > M) r1 = M;
  f32x4 mx = {0.f, 0.f, 0.f, 0.f};
  for (int r = r0; r < r1; ++r) {
    f32x4 v = *(const f32x4*)&x[(size_t)r * K + (size_t)c4 * 4];
#pragma unroll
    for (int i = 0; i < 4; ++i) mx[i] = fmaxf(mx[i], fabsf(v[i]));
  }
#pragma unroll
  for (int i = 0; i < 4; ++i)
    atomicMax(&cm[c4 * 4 + i], __float_as_uint(mx[i]));
}

// ---------------- row-wise quant-dequant -> bf16 operand ----------------
__global__ __launch_bounds__(256) void k_quant(
    const float* __restrict__ src, const u32* __restrict__ cm,
    const int* __restrict__ thr_i, u16* __restrict__ dst, int K,
    int exclude_outlier_from_max) {
  int row = blockIdx.x;
  int tid = threadIdx.x;
  float thr = load_thr(thr_i);
  const float* sr = src + (size_t)row * K;
  const float* cmf = (const float*)cm;

  float v[16];
  u32 omask = 0;
  float lmax = 0.f;
#pragma unroll
  for (int j = 0; j < 4; ++j) {
    int c4 = j * 256 + tid;
    f32x4 val = *(const f32x4*)&sr[c4 * 4];
    f32x4 cv = *(const f32x4*)&cmf[c4 * 4];
#pragma unroll
    for (int i = 0; i < 4; ++i) {
      float xv = val[i];
      v[j * 4 + i] = xv;
      bool is_out = cv[i] > thr;
      if (is_out) omask |= 1u << (j * 4 + i);
      if (!is_out || !exclude_outlier_from_max) lmax = fmaxf(lmax, fabsf(xv));
    }
  }
  float m = lmax;
#pragma unroll
  for (int off = 32; off >= 1; off >>= 1) m = fmaxf(m, __shfl_down(m, off));
  __shared__ float red[4];
  int lane = tid & 63, wv = tid >> 6;
  if (lane == 0) red[wv] = m;
  __syncthreads();
  float rm = fmaxf(fmaxf(red[0], red[1]), fmaxf(red[2], red[3]));
  float s = fmaxf(rm / 127.0f, 1e-8f);

#pragma unroll
  for (int j = 0; j < 4; ++j) {
    int c4 = j * 256 + tid;
    u16x4 ov;
#pragma unroll
    for (int i = 0; i < 4; ++i) {
      float xv = v[j * 4 + i];
      float dq;
      if (omask & (1u << (j * 4 + i))) {
        dq = xv;
      } else {
        float q = rintf(xv / s);
        q = fminf(fmaxf(q, -127.f), 127.f);
        dq = q * s;
      }
      ov[i] = f2bf(dq);
    }
    *(u16x4*)&dst[(size_t)row * K + c4 * 4] = ov;
  }
}

// ---------------- 256x256 8-phase bf16 GEMM (NT): out = A @ B^T + bias ----
// m201 template: BM=BN=256, BK=64, 8 waves (2x4), per-wave 128x64 output,
// 128 KiB LDS dbuf, full 3-bit slot swizzle (slot ^= row&7; inverse applied
// on the pre-swizzled global source, LDS dest linear — rule 21),
// counted vmcnt(4) at phases 4/8, setprio around MFMA clusters, XCD swizzle.
#define BM 256
#define BN 256

__global__ __launch_bounds__(512, 2) void k_gemm8(
    const u16* __restrict__ Aq, const u16* __restrict__ Bq,
    const float* __restrict__ bias, float* __restrict__ out, int M, int N,
    int K) {
  extern __shared__ u16 lds_raw[];
  // [buf][op A=0/B=1][half][128*64 u16] ; total 128 KiB
  u16(*lds)[2][2][128 * 64] = (u16(*)[2][2][128 * 64])lds_raw;

  int tid = threadIdx.x;
  int lane = tid & 63, wave = tid >> 6;
  int wm = wave >> 2, wn = wave & 3;  // 2 x 4 wave grid

  // T1: bijective XCD swizzle (nwg % 8 == 0)
  int nwg = gridDim.x;
  int bid = blockIdx.x;
  int swz = (bid & 7) * (nwg >> 3) + (bid >> 3);
  int nbn = N / BN;
  int bm = swz / nbn, bn = swz % nbn;
  int r0 = bm * BM, c0 = bn * BN;

  // staging: per thread 2x global_load_lds(16B) per half-tile (128x64 u16).
  // LDS half-tile = 1024 granules of 16B (8 granules per 128B row).
  // LDS dest linear (granule g); global source pre-swizzled so LDS granule
  // (row, gc) holds linear granule (row, gc ^ (row&7)) — involution.
  int g0 = tid, g1 = 512 + tid;
  int row0s = g0 >> 3, col0e = ((g0 & 7) ^ ((g0 >> 3) & 7)) << 3;
  int row1s = g1 >> 3, col1e = ((g1 & 7) ^ ((g1 >> 3) & 7)) << 3;

#define STAGE(dstp, srcb, rowbase, kb)                                        \
  {                                                                           \
    gload_lds16(&(srcb)[(size_t)((rowbase) + row0s) * K + (kb) + col0e],      \
                &(dstp)[(size_t)g0 * 8]);                                     \
    gload_lds16(&(srcb)[(size_t)((rowbase) + row1s) * K + (kb) + col1e],      \
                &(dstp)[(size_t)g1 * 8]);                                     \
  }

  // ds_read of one 16x16x32 fragment (8 bf16 = 16B), slot ^= row&7 swizzle
#define LDA(dst, buf, i, ks)                                                  \
  {                                                                           \
    int rl = (i) * 16 + (lane & 15);                                          \
    int off = rl * 128 + ((((ks) * 4 + (lane >> 4)) ^ (rl & 7)) << 4);        \
    dst = *(const bf16x8*)((const char*)lds[buf][0][wm] + off);               \
  }
#define LDB(dst, buf, j, ks)                                                  \
  {                                                                           \
    int rl = ((wn & 1) << 6) + (j) * 16 + (lane & 15);                        \
    int off = rl * 128 + ((((ks) * 4 + (lane >> 4)) ^ (rl & 7)) << 4);        \
    dst = *(const bf16x8*)((const char*)lds[buf][1][wn >> 1] + off);          \
  }

#define MF(i, j, av, bv) \
  acc[i][j] = __builtin_amdgcn_mfma_f32_16x16x32_bf16(av, bv, acc[i][j], 0, 0, 0)

  // one phase: quadrant q of buffer buf over full K=64; 16 MFMA
#define PHASE(buf, q, PREF, TAILWAIT)                                         \
  {                                                                           \
    if ((q) == 0) {                                                           \
      LDB(Bf[0], buf, 0, 0); LDB(Bf[1], buf, 1, 0);                           \
      LDB(Bf[2], buf, 2, 0); LDB(Bf[3], buf, 3, 0);                           \
      LDB(Bf[4], buf, 0, 1); LDB(Bf[5], buf, 1, 1);                           \
      LDB(Bf[6], buf, 2, 1); LDB(Bf[7], buf, 3, 1);                           \
    }                                                                         \
    bf16x8 a00, a01, a10, a11;                                                \
    LDA(a00, buf, 2 * (q), 0);                                                \
    LDA(a01, buf, 2 * (q), 1);                                                \
    LDA(a10, buf, 2 * (q) + 1, 0);                                            \
    LDA(a11, buf, 2 * (q) + 1, 1);                                            \
    PREF;                                                                     \
    __builtin_amdgcn_s_barrier();                                             \
    asm volatile("s_waitcnt lgkmcnt(0)" ::: "memory");                        \
    __builtin_amdgcn_sched_barrier(0);                                        \
    __builtin_amdgcn_s_setprio(1);                                            \
    MF(2 * (q), 0, a00, Bf[0]);                                               \
    MF(2 * (q), 1, a00, Bf[1]);                                               \
    MF(2 * (q), 2, a00, Bf[2]);                                               \
    MF(2 * (q), 3, a00, Bf[3]);                                               \
    MF(2 * (q) + 1, 0, a10, Bf[0]);                                           \
    MF(2 * (q) + 1, 1, a10, Bf[1]);                                           \
    MF(2 * (q) + 1, 2, a10, Bf[2]);                                           \
    MF(2 * (q) + 1, 3, a10, Bf[3]);                                           \
    MF(2 * (q), 0, a01, Bf[4]);                                               \
    MF(2 * (q), 1, a01, Bf[5]);                                               \
    MF(2 * (q), 2, a01, Bf[6]);                                               \
    MF(2 * (q), 3, a01, Bf[7]);                                               \
    MF(2 * (q) + 1, 0, a11, Bf[4]);                                           \
    MF(2 * (q) + 1, 1, a11, Bf[5]);                                           \
    MF(2 * (q) + 1, 2, a11, Bf[6]);                                           \
    MF(2 * (q) + 1, 3, a11, Bf[7]);                                           \
    __builtin_amdgcn_s_setprio(0);                                            \
    __builtin_amdgcn_sched_barrier(0);                                        \
    TAILWAIT;                                                                 \
    __builtin_amdgcn_s_barrier();                                             \
  }

  f32x4 acc[8][4] = {};
  bf16x8 Bf[8];

  // prologue: tile0 full into buf0, tile1 B-halves into buf1
  STAGE(lds[0][0][0], Aq, r0, 0);
  STAGE(lds[0][0][1], Aq, r0 + 128, 0);
  STAGE(lds[0][1][0], Bq, c0, 0);
  STAGE(lds[0][1][1], Bq, c0 + 128, 0);
  STAGE(lds[1][1][0], Bq, c0, 64);
  STAGE(lds[1][1][1], Bq, c0 + 128, 64);
  asm volatile("s_waitcnt vmcnt(4)" ::: "memory");
  __builtin_amdgcn_s_barrier();

  int nit = K / 128;  // 2 K-tiles per iteration
  for (int it = 0; it < nit; ++it) {
    int kt1 = it * 128 + 64;  // tile t+1 (always < K)
    int kb2 = it * 128 + 128;
    kb2 = (kb2 < K) ? kb2 : 0;  // tile t+2 (clamped; unused if OOB)
    int kb3 = it * 128 + 192;
    kb3 = (kb3 < K) ? kb3 : 0;  // tile t+3 (clamped)
    // phases 1-4: compute tile t from buf0
    PHASE(0, 0, STAGE(lds[1][0][0], Aq, r0, kt1), );
    PHASE(0, 1, STAGE(lds[1][0][1], Aq, r0 + 128, kt1), );
    PHASE(0, 2, STAGE(lds[0][1][0], Bq, c0, kb2), );
    PHASE(0, 3, STAGE(lds[0][1][1], Bq, c0 + 128, kb2),
          asm volatile("s_waitcnt vmcnt(4)" ::: "memory"));
    // phases 5-8: compute tile t+1 from buf1
    PHASE(1, 0, STAGE(lds[0][0][0], Aq, r0, kb2), );
    PHASE(1, 1, STAGE(lds[0][0][1], Aq, r0 + 128, kb2), );
    PHASE(1, 2, STAGE(lds[1][1][0], Bq, c0, kb3), );
    PHASE(1, 3, STAGE(lds[1][1][1], Bq, c0 + 128, kb3),
          asm volatile("s_waitcnt vmcnt(4)" ::: "memory"));
  }

  // epilogue: C/D layout col=lane&15, row=(lane>>4)*4+reg
  int lr = (lane >> 4) << 2, lc = lane & 15;
  float bv[4];
#pragma unroll
  for (int j = 0; j < 4; ++j) bv[j] = bias[c0 + wn * 64 + j * 16 + lc];
#pragma unroll
  for (int i = 0; i < 8; ++i) {
#pragma unroll
    for (int r = 0; r < 4; ++r) {
      int gm = r0 + wm * 128 + i * 16 + lr + r;
      float* orow = out + (size_t)gm * N + c0 + wn * 64 + lc;
#pragma unroll
      for (int j = 0; j < 4; ++j) orow[j * 16] = acc[i][j][r] + bv[j];
    }
  }
}

extern "C" void kernel_launch(void* const* d_in, const int* in_sizes, int n_in,
                              void* d_out, int out_size, void* d_ws,
                              size_t ws_size, hipStream_t stream) {
  const float* x = (const float*)d_in[0];
  const float* W = (const float*)d_in[1];
  const float* bias = (const float*)d_in[2];
  const int* thr = (const int*)d_in[3];
  float* out = (float*)d_out;

  int N = in_sizes[2];
  int K = in_sizes[1] / N;
  int M = in_sizes[0] / K;

  u32* cm = (u32*)d_ws;
  u16* Aq = (u16*)((char*)d_ws + 16384);
  u16* Bq = (u16*)((char*)d_ws + 16384 + (size_t)M * K * sizeof(u16));

  k_init_cm<<<dim3((K + 255) / 256), dim3(256), 0, stream>>>(cm, K);

  {
    int gx = K / 1024;
    int gy = 128;
    int rpb = (M + gy - 1) / gy;
    k_colmax<<<dim3(gx, gy), dim3(256), 0, stream>>>(x, cm, M, K, rpb);
  }

  k_quant<<<dim3(M), dim3(256), 0, stream>>>(x, cm, thr, Aq, K, 1);
  k_quant<<<dim3(N), dim3(256), 0, stream>>>(W, cm, thr, Bq, K, 0);

  (void)hipFuncSetAttribute((const void*)k_gemm8,
                            hipFuncAttributeMaxDynamicSharedMemorySize,
                            131072);
  int nwg = (M / BM) * (N / BN);
  k_gemm8<<<dim3(nwg), dim3(512), 131072, stream>>>(Aq, Bq, bias, out, M, N,
                                                    K);
}

// Round 4
// 321.387 us; speedup vs baseline: 1.4868x; 1.0027x over previous
//
#include <hip/hip_runtime.h>

typedef unsigned short u16;
typedef unsigned int u32;
typedef __attribute__((ext_vector_type(4))) float f32x4;
typedef __attribute__((ext_vector_type(8))) __bf16 bf16x8;
typedef __attribute__((ext_vector_type(4))) u16 u16x4;

__device__ __forceinline__ u16 f2bf(float f) {
  u32 u = __float_as_uint(f);
  u32 r = (u + 0x7fffu + ((u >> 16) & 1u)) >> 16;
  return (u16)r;
}

__device__ __forceinline__ float load_thr(const int* p) {
  int iv = *p;
  float fv = __int_as_float(iv);
  if (fv >= 1.0f && fv <= 1.0e6f) return fv;
  return (float)iv;
}

__device__ __forceinline__ void gload_lds16(const void* g, void* l) {
  __builtin_amdgcn_global_load_lds(
      (const __attribute__((address_space(1))) void*)g,
      (__attribute__((address_space(3))) void*)l, 16, 0, 0);
}

// ---------------- colmax over rows of x ----------------
__global__ void k_init_cm(u32* cm, int K) {
  int i = blockIdx.x * 256 + threadIdx.x;
  if (i < K) cm[i] = 0u;
}

__global__ __launch_bounds__(256) void k_colmax(const float* __restrict__ x,
                                                u32* __restrict__ cm, int M,
                                                int K, int rpb) {
  int c4 = blockIdx.x * 256 + threadIdx.x;
  int r0 = blockIdx.y * rpb;
  int r1 = r0 + rpb;
  if (r1 > M) r1 = M;
  f32x4 mx = {0.f, 0.f, 0.f, 0.f};
  for (int r = r0; r < r1; ++r) {
    f32x4 v = *(const f32x4*)&x[(size_t)r * K + (size_t)c4 * 4];
#pragma unroll
    for (int i = 0; i < 4; ++i) mx[i] = fmaxf(mx[i], fabsf(v[i]));
  }
#pragma unroll
  for (int i = 0; i < 4; ++i)
    atomicMax(&cm[c4 * 4 + i], __float_as_uint(mx[i]));
}

// ---------------- row-wise quant-dequant -> bf16 operand ----------------
__global__ __launch_bounds__(256) void k_quant(
    const float* __restrict__ src, const u32* __restrict__ cm,
    const int* __restrict__ thr_i, u16* __restrict__ dst, int K,
    int exclude_outlier_from_max) {
  int row = blockIdx.x;
  int tid = threadIdx.x;
  float thr = load_thr(thr_i);
  const float* sr = src + (size_t)row * K;
  const float* cmf = (const float*)cm;

  float v[16];
  u32 omask = 0;
  float lmax = 0.f;
#pragma unroll
  for (int j = 0; j < 4; ++j) {
    int c4 = j * 256 + tid;
    f32x4 val = *(const f32x4*)&sr[c4 * 4];
    f32x4 cv = *(const f32x4*)&cmf[c4 * 4];
#pragma unroll
    for (int i = 0; i < 4; ++i) {
      float xv = val[i];
      v[j * 4 + i] = xv;
      bool is_out = cv[i] > thr;
      if (is_out) omask |= 1u << (j * 4 + i);
      if (!is_out || !exclude_outlier_from_max) lmax = fmaxf(lmax, fabsf(xv));
    }
  }
  float m = lmax;
#pragma unroll
  for (int off = 32; off >= 1; off >>= 1) m = fmaxf(m, __shfl_down(m, off));
  __shared__ float red[4];
  int lane = tid & 63, wv = tid >> 6;
  if (lane == 0) red[wv] = m;
  __syncthreads();
  float rm = fmaxf(fmaxf(red[0], red[1]), fmaxf(red[2], red[3]));
  float s = fmaxf(rm / 127.0f, 1e-8f);

#pragma unroll
  for (int j = 0; j < 4; ++j) {
    int c4 = j * 256 + tid;
    u16x4 ov;
#pragma unroll
    for (int i = 0; i < 4; ++i) {
      float xv = v[j * 4 + i];
      float dq;
      if (omask & (1u << (j * 4 + i))) {
        dq = xv;
      } else {
        float q = rintf(xv / s);
        q = fminf(fmaxf(q, -127.f), 127.f);
        dq = q * s;
      }
      ov[i] = f2bf(dq);
    }
    *(u16x4*)&dst[(size_t)row * K + c4 * 4] = ov;
  }
}

// ---------------- 256x256 8-phase bf16 GEMM (NT): out = A @ B^T + bias ----
// m201 template: BM=BN=256, BK=64, 8 waves (2x4), per-wave 128x64 output,
// 128 KiB LDS dbuf, full 3-bit slot swizzle (slot ^= row&7; inverse applied
// on the pre-swizzled global source, LDS dest linear — rule 21),
// counted vmcnt(4) at phases 4/8, setprio around MFMA clusters, XCD swizzle.
// No sched_barrier pins (m141: source pinning defeats the scheduler).
#define BM 256
#define BN 256

__global__ __launch_bounds__(512, 2) void k_gemm8(
    const u16* __restrict__ Aq, const u16* __restrict__ Bq,
    const float* __restrict__ bias, float* __restrict__ out, int M, int N,
    int K) {
  extern __shared__ u16 lds_raw[];
  // [buf][op A=0/B=1][half][128*64 u16] ; total 128 KiB
  u16(*lds)[2][2][128 * 64] = (u16(*)[2][2][128 * 64])lds_raw;

  int tid = threadIdx.x;
  int lane = tid & 63, wave = tid >> 6;
  int wm = wave >> 2, wn = wave & 3;  // 2 x 4 wave grid

  // T1: bijective XCD swizzle (nwg % 8 == 0)
  int nwg = gridDim.x;
  int bid = blockIdx.x;
  int swz = (bid & 7) * (nwg >> 3) + (bid >> 3);
  int nbn = N / BN;
  int bm = swz / nbn, bn = swz % nbn;
  int r0 = bm * BM, c0 = bn * BN;

  // staging: per thread 2x global_load_lds(16B) per half-tile (128x64 u16).
  // LDS half-tile = 1024 granules of 16B (8 granules per 128B row).
  // LDS dest linear (granule g); global source pre-swizzled so LDS granule
  // (row, gc) holds linear granule (row, gc ^ (row&7)) — involution.
  int g0 = tid, g1 = 512 + tid;
  int row0s = g0 >> 3, col0e = ((g0 & 7) ^ ((g0 >> 3) & 7)) << 3;
  int row1s = g1 >> 3, col1e = ((g1 & 7) ^ ((g1 >> 3) & 7)) << 3;

#define STAGE(dstp, srcb, rowbase, kb)                                        \
  {                                                                           \
    gload_lds16(&(srcb)[(size_t)((rowbase) + row0s) * K + (kb) + col0e],      \
                &(dstp)[(size_t)g0 * 8]);                                     \
    gload_lds16(&(srcb)[(size_t)((rowbase) + row1s) * K + (kb) + col1e],      \
                &(dstp)[(size_t)g1 * 8]);                                     \
  }

  // ds_read of one 16x16x32 fragment (8 bf16 = 16B), slot ^= row&7 swizzle
#define LDA(dst, buf, i, ks)                                                  \
  {                                                                           \
    int rl = (i) * 16 + (lane & 15);                                          \
    int off = rl * 128 + ((((ks) * 4 + (lane >> 4)) ^ (rl & 7)) << 4);        \
    dst = *(const bf16x8*)((const char*)lds[buf][0][wm] + off);               \
  }
#define LDB(dst, buf, j, ks)                                                  \
  {                                                                           \
    int rl = ((wn & 1) << 6) + (j) * 16 + (lane & 15);                        \
    int off = rl * 128 + ((((ks) * 4 + (lane >> 4)) ^ (rl & 7)) << 4);        \
    dst = *(const bf16x8*)((const char*)lds[buf][1][wn >> 1] + off);          \
  }

#define MF(i, j, av, bv) \
  acc[i][j] = __builtin_amdgcn_mfma_f32_16x16x32_bf16(av, bv, acc[i][j], 0, 0, 0)

  // one phase: quadrant q of buffer buf over full K=64; 16 MFMA
#define PHASE(buf, q, PREF, TAILWAIT)                                         \
  {                                                                           \
    if ((q) == 0) {                                                           \
      LDB(Bf[0], buf, 0, 0); LDB(Bf[1], buf, 1, 0);                           \
      LDB(Bf[2], buf, 2, 0); LDB(Bf[3], buf, 3, 0);                           \
      LDB(Bf[4], buf, 0, 1); LDB(Bf[5], buf, 1, 1);                           \
      LDB(Bf[6], buf, 2, 1); LDB(Bf[7], buf, 3, 1);                           \
    }                                                                         \
    bf16x8 a00, a01, a10, a11;                                                \
    LDA(a00, buf, 2 * (q), 0);                                                \
    LDA(a01, buf, 2 * (q), 1);                                                \
    LDA(a10, buf, 2 * (q) + 1, 0);                                            \
    LDA(a11, buf, 2 * (q) + 1, 1);                                            \
    PREF;                                                                     \
    if ((q) == 0) asm volatile("s_waitcnt lgkmcnt(8)" ::: "memory");          \
    __builtin_amdgcn_s_barrier();                                             \
    asm volatile("s_waitcnt lgkmcnt(0)" ::: "memory");                        \
    __builtin_amdgcn_s_setprio(1);                                            \
    MF(2 * (q), 0, a00, Bf[0]);                                               \
    MF(2 * (q), 1, a00, Bf[1]);                                               \
    MF(2 * (q), 2, a00, Bf[2]);                                               \
    MF(2 * (q), 3, a00, Bf[3]);                                               \
    MF(2 * (q) + 1, 0, a10, Bf[0]);                                           \
    MF(2 * (q) + 1, 1, a10, Bf[1]);                                           \
    MF(2 * (q) + 1, 2, a10, Bf[2]);                                           \
    MF(2 * (q) + 1, 3, a10, Bf[3]);                                           \
    MF(2 * (q), 0, a01, Bf[4]);                                               \
    MF(2 * (q), 1, a01, Bf[5]);                                               \
    MF(2 * (q), 2, a01, Bf[6]);                                               \
    MF(2 * (q), 3, a01, Bf[7]);                                               \
    MF(2 * (q) + 1, 0, a11, Bf[4]);                                           \
    MF(2 * (q) + 1, 1, a11, Bf[5]);                                           \
    MF(2 * (q) + 1, 2, a11, Bf[6]);                                           \
    MF(2 * (q) + 1, 3, a11, Bf[7]);                                           \
    __builtin_amdgcn_s_setprio(0);                                            \
    TAILWAIT;                                                                 \
    __builtin_amdgcn_s_barrier();                                             \
  }

  f32x4 acc[8][4] = {};
  bf16x8 Bf[8];

  // prologue: tile0 full into buf0, tile1 B-halves into buf1
  STAGE(lds[0][0][0], Aq, r0, 0);
  STAGE(lds[0][0][1], Aq, r0 + 128, 0);
  STAGE(lds[0][1][0], Bq, c0, 0);
  STAGE(lds[0][1][1], Bq, c0 + 128, 0);
  STAGE(lds[1][1][0], Bq, c0, 64);
  STAGE(lds[1][1][1], Bq, c0 + 128, 64);
  asm volatile("s_waitcnt vmcnt(4)" ::: "memory");
  __builtin_amdgcn_s_barrier();

  int nit = K / 128;  // 2 K-tiles per iteration
  for (int it = 0; it < nit; ++it) {
    int kt1 = it * 128 + 64;  // tile t+1 (always < K)
    int kb2 = it * 128 + 128;
    kb2 = (kb2 < K) ? kb2 : 0;  // tile t+2 (clamped; unused if OOB)
    int kb3 = it * 128 + 192;
    kb3 = (kb3 < K) ? kb3 : 0;  // tile t+3 (clamped)
    // phases 1-4: compute tile t from buf0
    PHASE(0, 0, STAGE(lds[1][0][0], Aq, r0, kt1), );
    PHASE(0, 1, STAGE(lds[1][0][1], Aq, r0 + 128, kt1), );
    PHASE(0, 2, STAGE(lds[0][1][0], Bq, c0, kb2), );
    PHASE(0, 3, STAGE(lds[0][1][1], Bq, c0 + 128, kb2),
          asm volatile("s_waitcnt vmcnt(4)" ::: "memory"));
    // phases 5-8: compute tile t+1 from buf1
    PHASE(1, 0, STAGE(lds[0][0][0], Aq, r0, kb2), );
    PHASE(1, 1, STAGE(lds[0][0][1], Aq, r0 + 128, kb2), );
    PHASE(1, 2, STAGE(lds[1][1][0], Bq, c0, kb3), );
    PHASE(1, 3, STAGE(lds[1][1][1], Bq, c0 + 128, kb3),
          asm volatile("s_waitcnt vmcnt(4)" ::: "memory"));
  }

  // epilogue: C/D layout col=lane&15, row=(lane>>4)*4+reg
  int lr = (lane >> 4) << 2, lc = lane & 15;
  float bv[4];
#pragma unroll
  for (int j = 0; j < 4; ++j) bv[j] = bias[c0 + wn * 64 + j * 16 + lc];
#pragma unroll
  for (int i = 0; i < 8; ++i) {
#pragma unroll
    for (int r = 0; r < 4; ++r) {
      int gm = r0 + wm * 128 + i * 16 + lr + r;
      float* orow = out + (size_t)gm * N + c0 + wn * 64 + lc;
#pragma unroll
      for (int j = 0; j < 4; ++j) orow[j * 16] = acc[i][j][r] + bv[j];
    }
  }
}

extern "C" void kernel_launch(void* const* d_in, const int* in_sizes, int n_in,
                              void* d_out, int out_size, void* d_ws,
                              size_t ws_size, hipStream_t stream) {
  const float* x = (const float*)d_in[0];
  const float* W = (const float*)d_in[1];
  const float* bias = (const float*)d_in[2];
  const int* thr = (const int*)d_in[3];
  float* out = (float*)d_out;

  int N = in_sizes[2];
  int K = in_sizes[1] / N;
  int M = in_sizes[0] / K;

  u32* cm = (u32*)d_ws;
  u16* Aq = (u16*)((char*)d_ws + 16384);
  u16* Bq = (u16*)((char*)d_ws + 16384 + (size_t)M * K * sizeof(u16));

  k_init_cm<<<dim3((K + 255) / 256), dim3(256), 0, stream>>>(cm, K);

  {
    int gx = K / 1024;
    int gy = 128;
    int rpb = (M + gy - 1) / gy;
    k_colmax<<<dim3(gx, gy), dim3(256), 0, stream>>>(x, cm, M, K, rpb);
  }

  k_quant<<<dim3(M), dim3(256), 0, stream>>>(x, cm, thr, Aq, K, 1);
  k_quant<<<dim3(N), dim3(256), 0, stream>>>(W, cm, thr, Bq, K, 0);

  (void)hipFuncSetAttribute((const void*)k_gemm8,
                            hipFuncAttributeMaxDynamicSharedMemorySize,
                            131072);
  int nwg = (M / BM) * (N / BN);
  k_gemm8<<<dim3(nwg), dim3(512), 131072, stream>>>(Aq, Bq, bias, out, M, N,
                                                    K);
}